// Round 4
// baseline (266.420 us; speedup 1.0000x reference)
//
#include <hip/hip_runtime.h>
#include <hip/hip_bf16.h>
#include <cmath>

// R4: (a) re-fuse scatter+gemm1 (scatter blocks first); keep R3 gemm_dev
//     (operand swap + packed stores + reg-prefetch).
//     (b) agg critical-chain restructure: ev int4s loaded up-front in regs,
//     pass-0 gathers issued before the degree histogram (histogram from regs,
//     ballot fallback only for cnt>32), pass-1 addrs from regs.
//     (c) csr_agg_final: agg before Wl staging, single barrier.

#define IN_DIM 128
#define HID 64
#define OUT_DIM 40
#define NREL 8
#define NCOLS 576   // 8*64 (relations) + 64 (root)
#define CAP 64      // max in-degree bucket capacity
#define CSTR 16     // cursor stride (ints) = one 64B line per dst

typedef __attribute__((ext_vector_type(8))) short short8;
typedef __attribute__((ext_vector_type(4))) short short4v;
typedef __attribute__((ext_vector_type(4))) float floatx4;
typedef __attribute__((ext_vector_type(2))) float f32x2;

static __device__ __forceinline__ short f2bf(float f) {
  __hip_bfloat16 h = __float2bfloat16(f);
  return __builtin_bit_cast(short, h);
}
static __device__ __forceinline__ float bflo(unsigned int u) {
  return __int_as_float(u << 16);
}
static __device__ __forceinline__ float bfhi(unsigned int u) {
  return __int_as_float(u & 0xffff0000u);
}
static __device__ __forceinline__ unsigned int packbf(float x, float y) {
  unsigned int lo = (unsigned short)f2bf(x);
  unsigned int hi = (unsigned short)f2bf(y);
  return lo | (hi << 16);
}

// ---- pack Bt1, Bt2 + zero cursor (memset folded in) ------------------------
__global__ void pack_bt(const float* __restrict__ W1, const float* __restrict__ root1,
                        short* __restrict__ Bt1,
                        const float* __restrict__ W2, const float* __restrict__ root2,
                        short* __restrict__ Bt2,
                        int* __restrict__ cursor, int nzero4) {
  const int PB1 = (NCOLS * IN_DIM + 255) / 256;   // 288
  const int PB2 = (NCOLS * HID + 255) / 256;      // 144
  int b = blockIdx.x;
  if (b < PB1) {
    int i = b * 256 + threadIdx.x;
    if (i >= NCOLS * IN_DIM) return;
    int c = i / IN_DIM, k = i % IN_DIM;
    float v = (c < NREL * HID)
      ? W1[((size_t)(c >> 6) * IN_DIM + k) * HID + (c & 63)]
      : root1[(size_t)k * HID + (c - NREL * HID)];
    Bt1[i] = f2bf(v);
  } else if (b < PB1 + PB2) {
    int i = (b - PB1) * 256 + threadIdx.x;
    if (i >= NCOLS * HID) return;
    int c = i / HID, k = i % HID;
    float v = (c < NREL * HID)
      ? W2[((size_t)(c >> 6) * HID + k) * HID + (c & 63)]
      : root2[(size_t)k * HID + (c - NREL * HID)];
    Bt2[i] = f2bf(v);
  } else {
    int i = (b - PB1 - PB2) * 256 + threadIdx.x;
    if (i < nzero4) {
      int4 z; z.x = 0; z.y = 0; z.z = 0; z.w = 0;
      ((int4*)cursor)[i] = z;
    }
  }
}

// ---- shared MFMA GEMM body: C[64 x 576] = act(A tile) @ Bt^T ---------------
// Operand-swapped MFMA: lane (wv,quad,lm) holds row=16wv+lm,
// cols = cy*64 + nb*16 + quad*4 + (0..3) -> packed 8B stores.
// B tile cy+1 reg-prefetched before MFMA(cy).
// AMODE 0: A fp32, no relu.  AMODE 1: A bf16, relu.
template<int K, int AMODE>
__device__ __forceinline__ void gemm_dev(
    short* As, short* Bs,
    const void* __restrict__ Aptr, const short* __restrict__ Bt,
    const float* __restrict__ bias, short* __restrict__ H,
    unsigned short* __restrict__ AGG, int M, int row0)
{
  constexpr int AST = K + 8;
  constexpr int CB = K / 8;            // short8 chunks per 64-col B row
  constexpr int NCH = 64 * CB / 256;   // chunks per thread per tile (4 or 2)
  int tid = threadIdx.x;
  int wv = tid >> 6, lane = tid & 63;
  int lm = lane & 15, quad = lane >> 4;

  // per-thread B chunk coords (fixed across tiles)
  int bn[NCH], bko[NCH];
  #pragma unroll
  for (int j = 0; j < NCH; ++j) {
    int i = tid + j * 256;
    bn[j] = i / CB; bko[j] = i % CB;
  }

  // issue tile-0 B loads first (latency hidden under A staging)
  short8 breg[NCH];
  #pragma unroll
  for (int j = 0; j < NCH; ++j)
    breg[j] = *(const short8*)(Bt + (unsigned)(bn[j] * K + bko[j] * 8));

  if (AMODE == 0) {
    const float* A = (const float*)Aptr;
    constexpr int CH = K / 4;
    for (int i = tid; i < 64 * CH; i += 256) {
      int r = i / CH, kq = i % CH;
      int gr = row0 + r; if (gr >= M) gr = M - 1;
      float4 v = *(const float4*)(A + (unsigned)(gr * K + kq * 4));
      short4v s;
      s.x = f2bf(v.x); s.y = f2bf(v.y); s.z = f2bf(v.z); s.w = f2bf(v.w);
      *(short4v*)(As + r * AST + kq * 4) = s;
    }
  } else {
    const short* A = (const short*)Aptr;
    constexpr int CH = K / 8;
    for (int i = tid; i < 64 * CH; i += 256) {
      int r = i / CH, ko = i % CH;
      int gr = row0 + r; if (gr >= M) gr = M - 1;
      short8 v = *(const short8*)(A + (unsigned)(gr * K + ko * 8));
      #pragma unroll
      for (int j = 0; j < 8; ++j)
        if ((unsigned short)v[j] & 0x8000u) v[j] = 0;   // bf16 relu
      *(short8*)(As + r * AST + ko * 8) = v;
    }
  }

  const short* ap = As + (16 * wv + lm) * AST + quad * 8;
  int rowg = row0 + 16 * wv + lm;

  for (int cy = 0; cy < 9; ++cy) {
    // write current tile's prefetched regs to LDS
    #pragma unroll
    for (int j = 0; j < NCH; ++j)
      *(short8*)(Bs + bn[j] * AST + bko[j] * 8) = breg[j];
    __syncthreads();

    // issue next tile's loads before MFMA (latency hidden under MFMA)
    if (cy < 8) {
      #pragma unroll
      for (int j = 0; j < NCH; ++j)
        breg[j] = *(const short8*)(
            Bt + (unsigned)(((cy + 1) * 64 + bn[j]) * K + bko[j] * 8));
    }

    floatx4 acc[4] = {{0,0,0,0},{0,0,0,0},{0,0,0,0},{0,0,0,0}};
    #pragma unroll
    for (int ks = 0; ks < K / 32; ++ks) {
      short8 a = *(const short8*)(ap + ks * 32);
      #pragma unroll
      for (int nb = 0; nb < 4; ++nb) {
        short8 b = *(const short8*)(Bs + (nb * 16 + lm) * AST + ks * 32 + quad * 8);
        // swapped operands: lane holds one C-row, 4 cols
        acc[nb] = __builtin_amdgcn_mfma_f32_16x16x32_bf16(b, a, acc[nb], 0, 0, 0);
      }
    }
    __syncthreads();

    if (cy < 8) {
      if (rowg < M) {
        short* hrow = H + (unsigned)rowg * (NREL * HID) + cy * 64 + quad * 4;
        #pragma unroll
        for (int nb = 0; nb < 4; ++nb) {
          short4v s;
          s.x = f2bf(acc[nb][0]); s.y = f2bf(acc[nb][1]);
          s.z = f2bf(acc[nb][2]); s.w = f2bf(acc[nb][3]);
          *(short4v*)(hrow + nb * 16) = s;
        }
      }
    } else {
      if (rowg < M) {
        unsigned short* arow = AGG + (unsigned)rowg * HID + quad * 4;
        #pragma unroll
        for (int nb = 0; nb < 4; ++nb) {
          float4 bv = *(const float4*)(bias + nb * 16 + quad * 4);
          short4v s;
          s.x = f2bf(acc[nb][0] + bv.x); s.y = f2bf(acc[nb][1] + bv.y);
          s.z = f2bf(acc[nb][2] + bv.z); s.w = f2bf(acc[nb][3] + bv.w);
          *(short4v*)(arow + nb * 16) = s;
        }
      }
    }
  }
}

// ---- fused: scatter (blocks < SB) + gemm layer-1 (blocks >= SB) ------------
__global__ __launch_bounds__(256, 4) void gemm1_scatter(
    const float* __restrict__ A, const short* __restrict__ Bt,
    const float* __restrict__ bias, short* __restrict__ H,
    unsigned short* __restrict__ AGG, int M, int SB,
    const int* __restrict__ src, const int* __restrict__ dst,
    const int* __restrict__ et,
    int* __restrict__ cursor, int* __restrict__ ev, int E)
{
  constexpr int AST = IN_DIM + 8;
  __shared__ short As[64 * AST];
  __shared__ short Bs[64 * AST];
  if ((int)blockIdx.x >= SB) {
    gemm_dev<IN_DIM, 0>(As, Bs, A, Bt, bias, H, AGG, M, (blockIdx.x - SB) * 64);
  } else {
    int e = blockIdx.x * 256 + threadIdx.x;
    if (e >= E) return;
    int d = dst[e];
    int pos = atomicAdd(&cursor[d * CSTR], 1);
    if (pos < CAP)
      __builtin_nontemporal_store((src[e] << 3) | et[e], &ev[d * CAP + pos]);
  }
}

// ---- gemm layer 2 (bf16 A with relu) ---------------------------------------
__global__ __launch_bounds__(256, 4) void gemm2_mfma(
    const unsigned short* __restrict__ A, const short* __restrict__ Bt,
    const float* __restrict__ bias, short* __restrict__ H,
    unsigned short* __restrict__ AGG, int M)
{
  constexpr int AST = HID + 8;
  __shared__ short As[64 * AST];
  __shared__ short Bs[64 * AST];
  gemm_dev<HID, 1>(As, Bs, A, Bt, bias, H, AGG, M, blockIdx.x * 64);
}

// ---- agg core: HALF-WAVE per dst ------------------------------------------
// ev entries 0..31 arrive pre-loaded in registers (e0..e3); pass-0 gathers
// are issued before the degree histogram (computed from regs, ballots only
// for the rare cnt>32 tail). FMA order identical to prior rounds.
static __device__ __forceinline__ void agg_dst(
    const uint2* __restrict__ Hu2, const int* __restrict__ evr,
    int4 e0, int4 e1, int4 e2, int4 e3,
    int cnt, int qloc, int sub, int lhl, int h,
    float& a0, float& a1, float& a2, float& a3)
{
  int vv0[8] = {e0.x, e0.y, e0.z, e0.w, e1.x, e1.y, e1.z, e1.w};
  int vv1[8] = {e2.x, e2.y, e2.z, e2.w, e3.x, e3.y, e3.z, e3.w};
  int base0 = qloc * 8, base1 = 16 + qloc * 8;
  uint2 hv[8];

  // issue pass-0 gathers immediately (only needs cnt + reg ev values)
  #pragma unroll
  for (int i = 0; i < 8; ++i) {
    bool ok = (base0 + i) < cnt;
    int v = ok ? vv0[i] : 0;
    hv[i] = Hu2[(unsigned)v * 16u + (unsigned)sub];
  }

  // degree histogram from registers, while gathers are in flight
  int myrel = lhl & 7;
  int c = 0;
  #pragma unroll
  for (int i = 0; i < 8; ++i)
    c += ((base0 + i) < cnt && (vv0[i] & 7) == myrel) ? 1 : 0;
  #pragma unroll
  for (int i = 0; i < 8; ++i)
    c += ((base1 + i) < cnt && (vv1[i] & 7) == myrel) ? 1 : 0;
  c += __shfl_xor(c, 16, 64);   // other qloc group of this half
  if (cnt > 32) {               // rare tail: entries 32..63 via ballots
    int eu = evr[32 + lhl];
    bool valid = (32 + lhl) < cnt;
    unsigned long long hm = 0xffffffffull << (h * 32);
    int rr = eu & 7;
    #pragma unroll
    for (int r = 0; r < 8; ++r) {
      unsigned long long m = __ballot(valid && rr == r);
      int cr = __popcll(m & hm);
      if (myrel == r) c += cr;
    }
  }
  float wreg = (c > 0) ? (1.0f / (float)c) : 0.0f;

  f32x2 A01 = {a0, a1}, A23 = {a2, a3};
  // consume pass 0
  #pragma unroll
  for (int i = 0; i < 8; ++i) {
    bool ok = (base0 + i) < cnt;
    float w0 = __shfl(wreg, h * 32 + (vv0[i] & 7), 64);
    float w = ok ? w0 : 0.f;
    f32x2 w2 = {w, w};
    f32x2 h01 = {bflo(hv[i].x), bfhi(hv[i].x)};
    f32x2 h23 = {bflo(hv[i].y), bfhi(hv[i].y)};
    A01 += h01 * w2;
    A23 += h23 * w2;
  }
  // pass 1 (entries 16..31): addresses from regs
  if (cnt > 16) {
    #pragma unroll
    for (int i = 0; i < 8; ++i) {
      bool ok = (base1 + i) < cnt;
      int v = ok ? vv1[i] : 0;
      hv[i] = Hu2[(unsigned)v * 16u + (unsigned)sub];
    }
    #pragma unroll
    for (int i = 0; i < 8; ++i) {
      bool ok = (base1 + i) < cnt;
      float w0 = __shfl(wreg, h * 32 + (vv1[i] & 7), 64);
      float w = ok ? w0 : 0.f;
      f32x2 w2 = {w, w};
      f32x2 h01 = {bflo(hv[i].x), bfhi(hv[i].x)};
      f32x2 h23 = {bflo(hv[i].y), bfhi(hv[i].y)};
      A01 += h01 * w2;
      A23 += h23 * w2;
    }
  }
  // passes 2..3 (entries 32..63): rare, load from ev
  if (cnt > 32) {
    #pragma unroll
    for (int P = 2; P < 4; ++P) {
      if (cnt > P * 16) {
        const int4* pp = (const int4*)(evr + P * 16 + qloc * 8);
        int4 f0 = pp[0], f1 = pp[1];
        int vv[8] = {f0.x, f0.y, f0.z, f0.w, f1.x, f1.y, f1.z, f1.w};
        int bs = P * 16 + qloc * 8;
        #pragma unroll
        for (int i = 0; i < 8; ++i) {
          bool ok = (bs + i) < cnt;
          int v = ok ? vv[i] : 0;
          hv[i] = Hu2[(unsigned)v * 16u + (unsigned)sub];
        }
        #pragma unroll
        for (int i = 0; i < 8; ++i) {
          bool ok = (bs + i) < cnt;
          float w0 = __shfl(wreg, h * 32 + (vv[i] & 7), 64);
          float w = ok ? w0 : 0.f;
          f32x2 w2 = {w, w};
          f32x2 h01 = {bflo(hv[i].x), bfhi(hv[i].x)};
          f32x2 h23 = {bflo(hv[i].y), bfhi(hv[i].y)};
          A01 += h01 * w2;
          A23 += h23 * w2;
        }
      }
    }
  }
  a0 = A01.x; a1 = A01.y; a2 = A23.x; a3 = A23.y;
  a0 += __shfl_xor(a0, 16, 64);
  a1 += __shfl_xor(a1, 16, 64);
  a2 += __shfl_xor(a2, 16, 64);
  a3 += __shfl_xor(a3, 16, 64);
}

// ---- layer-1 aggregation: 2 dsts per wave, AGG(bf16) += mean-messages ------
__global__ __launch_bounds__(256) void csr_agg(
    const short* __restrict__ H, const int* __restrict__ cursor,
    const int* __restrict__ ev, unsigned short* __restrict__ AGG, int N)
{
  int tid = threadIdx.x;
  int wv = tid >> 6, lane = tid & 63;
  int h = lane >> 5, lhl = lane & 31, qloc = lhl >> 4, sub = lhl & 15;
  int d = blockIdx.x * 8 + wv * 2 + h;
  int dc = d < N ? d : N - 1;

  // all prologue loads issued together (independent)
  int cnt = cursor[dc * CSTR];
  const int* evr = ev + dc * CAP;
  const int4* p0 = (const int4*)(evr + qloc * 8);
  int4 e0 = p0[0], e1 = p0[1];
  const int4* p1 = (const int4*)(evr + 16 + qloc * 8);
  int4 e2 = p1[0], e3 = p1[1];
  uint2* aggrow = (uint2*)(AGG + (size_t)dc * HID);
  uint2 iv = {0, 0};
  if (qloc == 0) iv = aggrow[sub];
  if (cnt > CAP) cnt = CAP;

  float a0 = 0.f, a1 = 0.f, a2 = 0.f, a3 = 0.f;
  if (qloc == 0) {
    a0 = bflo(iv.x); a1 = bfhi(iv.x); a2 = bflo(iv.y); a3 = bfhi(iv.y);
  }
  agg_dst((const uint2*)H, evr, e0, e1, e2, e3, cnt, qloc, sub, lhl, h,
          a0, a1, a2, a3);
  if (d < N && qloc == 0) {
    uint2 ov;
    ov.x = packbf(a0, a1);
    ov.y = packbf(a2, a3);
    aggrow[sub] = ov;
  }
}

// ---- layer-2 aggregation (2 dsts/wave) + relu -> @Wl+bl -> log_softmax -----
__global__ __launch_bounds__(256) void csr_agg_final(
    const short* __restrict__ H, const int* __restrict__ cursor,
    const int* __restrict__ ev, const unsigned short* __restrict__ AGG,
    const float* __restrict__ Wl, const float* __restrict__ bl,
    float* __restrict__ out, int N)
{
  __shared__ float sWl[HID * OUT_DIM];
  __shared__ float sbl[OUT_DIM];
  __shared__ float sh[8][HID];
  int tid = threadIdx.x;
  int wv = tid >> 6, lane = tid & 63;
  int h = lane >> 5, lhl = lane & 31, qloc = lhl >> 4, sub = lhl & 15;
  int d = blockIdx.x * 8 + wv * 2 + h;
  int dc = d < N ? d : N - 1;

  // all prologue loads issued together (independent)
  int cnt = cursor[dc * CSTR];
  const int* evr = ev + dc * CAP;
  const int4* p0 = (const int4*)(evr + qloc * 8);
  int4 e0 = p0[0], e1 = p0[1];
  const int4* p1 = (const int4*)(evr + 16 + qloc * 8);
  int4 e2 = p1[0], e3 = p1[1];
  uint2 iv = ((const uint2*)(AGG + (size_t)dc * HID))[sub];
  if (cnt > CAP) cnt = CAP;

  float a0 = 0.f, a1 = 0.f, a2 = 0.f, a3 = 0.f;
  if (qloc == 0) {
    a0 = bflo(iv.x); a1 = bfhi(iv.x); a2 = bflo(iv.y); a3 = bfhi(iv.y);
  }
  agg_dst((const uint2*)H, evr, e0, e1, e2, e3, cnt, qloc, sub, lhl, h,
          a0, a1, a2, a3);
  if (qloc == 0) {
    float4 v;
    v.x = fmaxf(a0, 0.f); v.y = fmaxf(a1, 0.f);
    v.z = fmaxf(a2, 0.f); v.w = fmaxf(a3, 0.f);
    *(float4*)(&sh[wv * 2 + h][4 * sub]) = v;   // same-wave consumer, no barrier
  }

  // cooperative Wl staging after agg (L2-hot after first blocks)
  for (int i = tid; i < HID * OUT_DIM; i += 256) sWl[i] = Wl[i];
  if (tid < OUT_DIM) sbl[tid] = bl[tid];
  __syncthreads();

  // each wave finishes its 2 dsts sequentially
  #pragma unroll
  for (int ii = 0; ii < 2; ++ii) {
    int dd = blockIdx.x * 8 + wv * 2 + ii;
    const float* row = sh[wv * 2 + ii];
    float logit = -__builtin_inff();
    if (lane < OUT_DIM) {
      float t = sbl[lane];
      #pragma unroll 8
      for (int k = 0; k < HID; ++k) t += row[k] * sWl[k * OUT_DIM + lane];
      logit = t;
    }
    float m = logit;
    #pragma unroll
    for (int o = 32; o > 0; o >>= 1) m = fmaxf(m, __shfl_xor(m, o, 64));
    float ex = (lane < OUT_DIM) ? expf(logit - m) : 0.f;
    float s = ex;
    #pragma unroll
    for (int o = 32; o > 0; o >>= 1) s += __shfl_xor(s, o, 64);
    if (dd < N && lane < OUT_DIM)
      out[(size_t)dd * OUT_DIM + lane] = logit - m - logf(s);
  }
}

// ---- launch ----------------------------------------------------------------
extern "C" void kernel_launch(void* const* d_in, const int* in_sizes, int n_in,
                              void* d_out, int out_size, void* d_ws, size_t ws_size,
                              hipStream_t stream) {
  const float* x     = (const float*)d_in[0];
  const int*   eidx  = (const int*)d_in[1];
  const int*   etype = (const int*)d_in[2];
  const float* W1    = (const float*)d_in[3];
  const float* root1 = (const float*)d_in[4];
  const float* b1    = (const float*)d_in[5];
  const float* W2    = (const float*)d_in[6];
  const float* root2 = (const float*)d_in[7];
  const float* b2    = (const float*)d_in[8];
  const float* Wl    = (const float*)d_in[9];
  const float* bl    = (const float*)d_in[10];

  int N = in_sizes[0] / IN_DIM;   // 50000
  int E = in_sizes[2];            // 800000
  const int* srcp = eidx;
  const int* dstp = eidx + E;

  char* ws = (char*)d_ws;
  size_t off = 0;
  auto alloc = [&](size_t bytes) -> char* {
    char* p = ws + off;
    off += (bytes + 255) & ~(size_t)255;
    return p;
  };
  short* Bt1    = (short*)alloc((size_t)NCOLS * IN_DIM * 2);
  short* Bt2    = (short*)alloc((size_t)NCOLS * HID * 2);
  int*   cursor = (int*)alloc((size_t)N * CSTR * 4);           // 3.2 MB padded
  int*   ev     = (int*)alloc((size_t)N * CAP * 4);            // 12.8 MB
  short* H1     = (short*)alloc((size_t)N * NREL * HID * 2);   // 51.2 MB bf16
  short* H2     = (short*)alloc((size_t)N * NREL * HID * 2);   // 51.2 MB bf16
  unsigned short* AGG1 = (unsigned short*)alloc((size_t)N * HID * 2);
  unsigned short* AGG2 = (unsigned short*)alloc((size_t)N * HID * 2);

  const int PB1 = (NCOLS * IN_DIM + 255) / 256;   // 288
  const int PB2 = (NCOLS * HID + 255) / 256;      // 144
  int nzero4 = (N * CSTR) / 4;                    // int4 count for cursor zero
  int ZB = (nzero4 + 255) / 256;                  // 782
  pack_bt<<<PB1 + PB2 + ZB, 256, 0, stream>>>(W1, root1, Bt1, W2, root2, Bt2,
                                              cursor, nzero4);

  int GB = (N + 63) / 64;          // 782 gemm blocks
  int SB = (E + 255) / 256;        // 3125 scatter blocks
  gemm1_scatter<<<SB + GB, 256, 0, stream>>>(x, Bt1, b1, H1, AGG1, N, SB,
                                             srcp, dstp, etype, cursor, ev, E);

  csr_agg<<<(N + 7) / 8, 256, 0, stream>>>(H1, cursor, ev, AGG1, N);

  gemm2_mfma<<<GB, 256, 0, stream>>>(AGG1, Bt2, b2, H2, AGG2, N);

  csr_agg_final<<<(N + 7) / 8, 256, 0, stream>>>(H2, cursor, ev, AGG2,
                                                 Wl, bl, (float*)d_out, N);
}

// Round 5
// 249.638 us; speedup vs baseline: 1.0672x; 1.0672x over previous
//
#include <hip/hip_runtime.h>
#include <hip/hip_bf16.h>
#include <cmath>

// R5: (a) fused gemm1_scatter restored to R2 ordering (gemm blocks FIRST,
//     scatter trailing -- proven 54us; R4's scatter-first serialized, 105us).
//     (b) csr_agg + gemm2 fused into agg_gemm2: phase A = R4 agg_dst per
//     half-wave writing relu'd bf16 rows straight into the gemm A-tile in LDS
//     (bitwise-identical to AGG1 roundtrip); phase B = gemm_dev AMODE2
//     (A pre-staged). Kills AGG1 traffic + launch + inter-phase barrier.

#define IN_DIM 128
#define HID 64
#define OUT_DIM 40
#define NREL 8
#define NCOLS 576   // 8*64 (relations) + 64 (root)
#define CAP 64      // max in-degree bucket capacity
#define CSTR 16     // cursor stride (ints) = one 64B line per dst

typedef __attribute__((ext_vector_type(8))) short short8;
typedef __attribute__((ext_vector_type(4))) short short4v;
typedef __attribute__((ext_vector_type(4))) float floatx4;
typedef __attribute__((ext_vector_type(2))) float f32x2;

static __device__ __forceinline__ short f2bf(float f) {
  __hip_bfloat16 h = __float2bfloat16(f);
  return __builtin_bit_cast(short, h);
}
static __device__ __forceinline__ float bflo(unsigned int u) {
  return __int_as_float(u << 16);
}
static __device__ __forceinline__ float bfhi(unsigned int u) {
  return __int_as_float(u & 0xffff0000u);
}
static __device__ __forceinline__ unsigned int packbf(float x, float y) {
  unsigned int lo = (unsigned short)f2bf(x);
  unsigned int hi = (unsigned short)f2bf(y);
  return lo | (hi << 16);
}

// ---- pack Bt1, Bt2 + zero cursor (memset folded in) ------------------------
__global__ void pack_bt(const float* __restrict__ W1, const float* __restrict__ root1,
                        short* __restrict__ Bt1,
                        const float* __restrict__ W2, const float* __restrict__ root2,
                        short* __restrict__ Bt2,
                        int* __restrict__ cursor, int nzero4) {
  const int PB1 = (NCOLS * IN_DIM + 255) / 256;   // 288
  const int PB2 = (NCOLS * HID + 255) / 256;      // 144
  int b = blockIdx.x;
  if (b < PB1) {
    int i = b * 256 + threadIdx.x;
    if (i >= NCOLS * IN_DIM) return;
    int c = i / IN_DIM, k = i % IN_DIM;
    float v = (c < NREL * HID)
      ? W1[((size_t)(c >> 6) * IN_DIM + k) * HID + (c & 63)]
      : root1[(size_t)k * HID + (c - NREL * HID)];
    Bt1[i] = f2bf(v);
  } else if (b < PB1 + PB2) {
    int i = (b - PB1) * 256 + threadIdx.x;
    if (i >= NCOLS * HID) return;
    int c = i / HID, k = i % HID;
    float v = (c < NREL * HID)
      ? W2[((size_t)(c >> 6) * HID + k) * HID + (c & 63)]
      : root2[(size_t)k * HID + (c - NREL * HID)];
    Bt2[i] = f2bf(v);
  } else {
    int i = (b - PB1 - PB2) * 256 + threadIdx.x;
    if (i < nzero4) {
      int4 z; z.x = 0; z.y = 0; z.z = 0; z.w = 0;
      ((int4*)cursor)[i] = z;
    }
  }
}

// ---- shared MFMA GEMM body: C[64 x 576] = act(A tile) @ Bt^T ---------------
// Operand-swapped MFMA: lane (wv,quad,lm) holds row=16wv+lm,
// cols = cy*64 + nb*16 + quad*4 + (0..3) -> packed 8B stores.
// B tile cy+1 reg-prefetched before MFMA(cy).
// AMODE 0: A fp32, no relu.  AMODE 1: A bf16, relu.  AMODE 2: A already in LDS.
template<int K, int AMODE>
__device__ __forceinline__ void gemm_dev(
    short* As, short* Bs,
    const void* __restrict__ Aptr, const short* __restrict__ Bt,
    const float* __restrict__ bias, short* __restrict__ H,
    unsigned short* __restrict__ AGG, int M, int row0)
{
  constexpr int AST = K + 8;
  constexpr int CB = K / 8;            // short8 chunks per 64-col B row
  constexpr int NCH = 64 * CB / 256;   // chunks per thread per tile (4 or 2)
  int tid = threadIdx.x;
  int wv = tid >> 6, lane = tid & 63;
  int lm = lane & 15, quad = lane >> 4;

  // per-thread B chunk coords (fixed across tiles)
  int bn[NCH], bko[NCH];
  #pragma unroll
  for (int j = 0; j < NCH; ++j) {
    int i = tid + j * 256;
    bn[j] = i / CB; bko[j] = i % CB;
  }

  // issue tile-0 B loads first (latency hidden under A staging)
  short8 breg[NCH];
  #pragma unroll
  for (int j = 0; j < NCH; ++j)
    breg[j] = *(const short8*)(Bt + (unsigned)(bn[j] * K + bko[j] * 8));

  if constexpr (AMODE == 0) {
    const float* A = (const float*)Aptr;
    constexpr int CH = K / 4;
    for (int i = tid; i < 64 * CH; i += 256) {
      int r = i / CH, kq = i % CH;
      int gr = row0 + r; if (gr >= M) gr = M - 1;
      float4 v = *(const float4*)(A + (unsigned)(gr * K + kq * 4));
      short4v s;
      s.x = f2bf(v.x); s.y = f2bf(v.y); s.z = f2bf(v.z); s.w = f2bf(v.w);
      *(short4v*)(As + r * AST + kq * 4) = s;
    }
  } else if constexpr (AMODE == 1) {
    const short* A = (const short*)Aptr;
    constexpr int CH = K / 8;
    for (int i = tid; i < 64 * CH; i += 256) {
      int r = i / CH, ko = i % CH;
      int gr = row0 + r; if (gr >= M) gr = M - 1;
      short8 v = *(const short8*)(A + (unsigned)(gr * K + ko * 8));
      #pragma unroll
      for (int j = 0; j < 8; ++j)
        if ((unsigned short)v[j] & 0x8000u) v[j] = 0;   // bf16 relu
      *(short8*)(As + r * AST + ko * 8) = v;
    }
  }
  // AMODE 2: caller already filled As (this block's LDS)

  const short* ap = As + (16 * wv + lm) * AST + quad * 8;
  int rowg = row0 + 16 * wv + lm;

  for (int cy = 0; cy < 9; ++cy) {
    // write current tile's prefetched regs to LDS
    #pragma unroll
    for (int j = 0; j < NCH; ++j)
      *(short8*)(Bs + bn[j] * AST + bko[j] * 8) = breg[j];
    __syncthreads();

    // issue next tile's loads before MFMA (latency hidden under MFMA)
    if (cy < 8) {
      #pragma unroll
      for (int j = 0; j < NCH; ++j)
        breg[j] = *(const short8*)(
            Bt + (unsigned)(((cy + 1) * 64 + bn[j]) * K + bko[j] * 8));
    }

    floatx4 acc[4] = {{0,0,0,0},{0,0,0,0},{0,0,0,0},{0,0,0,0}};
    #pragma unroll
    for (int ks = 0; ks < K / 32; ++ks) {
      short8 a = *(const short8*)(ap + ks * 32);
      #pragma unroll
      for (int nb = 0; nb < 4; ++nb) {
        short8 b = *(const short8*)(Bs + (nb * 16 + lm) * AST + ks * 32 + quad * 8);
        // swapped operands: lane holds one C-row, 4 cols
        acc[nb] = __builtin_amdgcn_mfma_f32_16x16x32_bf16(b, a, acc[nb], 0, 0, 0);
      }
    }
    __syncthreads();

    if (cy < 8) {
      if (rowg < M) {
        short* hrow = H + (unsigned)rowg * (NREL * HID) + cy * 64 + quad * 4;
        #pragma unroll
        for (int nb = 0; nb < 4; ++nb) {
          short4v s;
          s.x = f2bf(acc[nb][0]); s.y = f2bf(acc[nb][1]);
          s.z = f2bf(acc[nb][2]); s.w = f2bf(acc[nb][3]);
          *(short4v*)(hrow + nb * 16) = s;
        }
      }
    } else {
      if (rowg < M) {
        unsigned short* arow = AGG + (unsigned)rowg * HID + quad * 4;
        #pragma unroll
        for (int nb = 0; nb < 4; ++nb) {
          float4 bv = *(const float4*)(bias + nb * 16 + quad * 4);
          short4v s;
          s.x = f2bf(acc[nb][0] + bv.x); s.y = f2bf(acc[nb][1] + bv.y);
          s.z = f2bf(acc[nb][2] + bv.z); s.w = f2bf(acc[nb][3] + bv.w);
          *(short4v*)(arow + nb * 16) = s;
        }
      }
    }
  }
}

// ---- fused: gemm layer-1 (blocks < GB) + bucket scatter (blocks >= GB) -----
// NOTE: gemm blocks FIRST (R2-proven ordering; scatter overlaps gemm phase).
__global__ __launch_bounds__(256, 4) void gemm1_scatter(
    const float* __restrict__ A, const short* __restrict__ Bt,
    const float* __restrict__ bias, short* __restrict__ H,
    unsigned short* __restrict__ AGG, int M, int GB,
    const int* __restrict__ src, const int* __restrict__ dst,
    const int* __restrict__ et,
    int* __restrict__ cursor, int* __restrict__ ev, int E)
{
  constexpr int AST = IN_DIM + 8;
  __shared__ short As[64 * AST];
  __shared__ short Bs[64 * AST];
  if ((int)blockIdx.x < GB) {
    gemm_dev<IN_DIM, 0>(As, Bs, A, Bt, bias, H, AGG, M, blockIdx.x * 64);
  } else {
    int e = (blockIdx.x - GB) * 256 + threadIdx.x;
    if (e >= E) return;
    int d = dst[e];
    int pos = atomicAdd(&cursor[d * CSTR], 1);
    if (pos < CAP)
      __builtin_nontemporal_store((src[e] << 3) | et[e], &ev[d * CAP + pos]);
  }
}

// ---- agg core: HALF-WAVE per dst ------------------------------------------
// ev entries 0..31 arrive pre-loaded in registers (e0..e3); pass-0 gathers
// are issued before the degree histogram (computed from regs, ballots only
// for the rare cnt>32 tail). FMA order identical to prior rounds.
static __device__ __forceinline__ void agg_dst(
    const uint2* __restrict__ Hu2, const int* __restrict__ evr,
    int4 e0, int4 e1, int4 e2, int4 e3,
    int cnt, int qloc, int sub, int lhl, int h,
    float& a0, float& a1, float& a2, float& a3)
{
  int vv0[8] = {e0.x, e0.y, e0.z, e0.w, e1.x, e1.y, e1.z, e1.w};
  int vv1[8] = {e2.x, e2.y, e2.z, e2.w, e3.x, e3.y, e3.z, e3.w};
  int base0 = qloc * 8, base1 = 16 + qloc * 8;
  uint2 hv[8];

  // issue pass-0 gathers immediately (only needs cnt + reg ev values)
  #pragma unroll
  for (int i = 0; i < 8; ++i) {
    bool ok = (base0 + i) < cnt;
    int v = ok ? vv0[i] : 0;
    hv[i] = Hu2[(unsigned)v * 16u + (unsigned)sub];
  }

  // degree histogram from registers, while gathers are in flight
  int myrel = lhl & 7;
  int c = 0;
  #pragma unroll
  for (int i = 0; i < 8; ++i)
    c += ((base0 + i) < cnt && (vv0[i] & 7) == myrel) ? 1 : 0;
  #pragma unroll
  for (int i = 0; i < 8; ++i)
    c += ((base1 + i) < cnt && (vv1[i] & 7) == myrel) ? 1 : 0;
  c += __shfl_xor(c, 16, 64);   // other qloc group of this half
  if (cnt > 32) {               // rare tail: entries 32..63 via ballots
    int eu = evr[32 + lhl];
    bool valid = (32 + lhl) < cnt;
    unsigned long long hm = 0xffffffffull << (h * 32);
    int rr = eu & 7;
    #pragma unroll
    for (int r = 0; r < 8; ++r) {
      unsigned long long m = __ballot(valid && rr == r);
      int cr = __popcll(m & hm);
      if (myrel == r) c += cr;
    }
  }
  float wreg = (c > 0) ? (1.0f / (float)c) : 0.0f;

  f32x2 A01 = {a0, a1}, A23 = {a2, a3};
  // consume pass 0
  #pragma unroll
  for (int i = 0; i < 8; ++i) {
    bool ok = (base0 + i) < cnt;
    float w0 = __shfl(wreg, h * 32 + (vv0[i] & 7), 64);
    float w = ok ? w0 : 0.f;
    f32x2 w2 = {w, w};
    f32x2 h01 = {bflo(hv[i].x), bfhi(hv[i].x)};
    f32x2 h23 = {bflo(hv[i].y), bfhi(hv[i].y)};
    A01 += h01 * w2;
    A23 += h23 * w2;
  }
  // pass 1 (entries 16..31): addresses from regs
  if (cnt > 16) {
    #pragma unroll
    for (int i = 0; i < 8; ++i) {
      bool ok = (base1 + i) < cnt;
      int v = ok ? vv1[i] : 0;
      hv[i] = Hu2[(unsigned)v * 16u + (unsigned)sub];
    }
    #pragma unroll
    for (int i = 0; i < 8; ++i) {
      bool ok = (base1 + i) < cnt;
      float w0 = __shfl(wreg, h * 32 + (vv1[i] & 7), 64);
      float w = ok ? w0 : 0.f;
      f32x2 w2 = {w, w};
      f32x2 h01 = {bflo(hv[i].x), bfhi(hv[i].x)};
      f32x2 h23 = {bflo(hv[i].y), bfhi(hv[i].y)};
      A01 += h01 * w2;
      A23 += h23 * w2;
    }
  }
  // passes 2..3 (entries 32..63): rare, load from ev
  if (cnt > 32) {
    #pragma unroll
    for (int P = 2; P < 4; ++P) {
      if (cnt > P * 16) {
        const int4* pp = (const int4*)(evr + P * 16 + qloc * 8);
        int4 f0 = pp[0], f1 = pp[1];
        int vv[8] = {f0.x, f0.y, f0.z, f0.w, f1.x, f1.y, f1.z, f1.w};
        int bs = P * 16 + qloc * 8;
        #pragma unroll
        for (int i = 0; i < 8; ++i) {
          bool ok = (bs + i) < cnt;
          int v = ok ? vv[i] : 0;
          hv[i] = Hu2[(unsigned)v * 16u + (unsigned)sub];
        }
        #pragma unroll
        for (int i = 0; i < 8; ++i) {
          bool ok = (bs + i) < cnt;
          float w0 = __shfl(wreg, h * 32 + (vv[i] & 7), 64);
          float w = ok ? w0 : 0.f;
          f32x2 w2 = {w, w};
          f32x2 h01 = {bflo(hv[i].x), bfhi(hv[i].x)};
          f32x2 h23 = {bflo(hv[i].y), bfhi(hv[i].y)};
          A01 += h01 * w2;
          A23 += h23 * w2;
        }
      }
    }
  }
  a0 = A01.x; a1 = A01.y; a2 = A23.x; a3 = A23.y;
  a0 += __shfl_xor(a0, 16, 64);
  a1 += __shfl_xor(a1, 16, 64);
  a2 += __shfl_xor(a2, 16, 64);
  a3 += __shfl_xor(a3, 16, 64);
}

// ---- fused layer-1 agg + layer-2 gemm: one block = 64 dsts -----------------
// Phase A: each half-wave aggregates 8 dsts (gather H1 rows, mean per rel,
// add AGG1 seed) and writes relu'd bf16 rows into the gemm A-tile (LDS).
// Phase B: gemm_dev<HID,2> computes H2 + AGG2 from the LDS tile.
// f2bf(fmaxf(a,0)) == relu-on-bf16(f2bf(a)) -> bitwise identical to the
// previous AGG1-roundtrip + gemm2 AMODE1 path.
__global__ __launch_bounds__(256) void agg_gemm2(
    const short* __restrict__ H1, const int* __restrict__ cursor,
    const int* __restrict__ ev, const unsigned short* __restrict__ AGG1,
    const short* __restrict__ Bt2, const float* __restrict__ bias2,
    short* __restrict__ H2, unsigned short* __restrict__ AGG2, int N)
{
  constexpr int AST = HID + 8;
  __shared__ short As[64 * AST];
  __shared__ short Bs[64 * AST];
  int tid = threadIdx.x;
  int wv = tid >> 6, lane = tid & 63;
  int h = lane >> 5, lhl = lane & 31, qloc = lhl >> 4, sub = lhl & 15;
  int hw = wv * 2 + h;              // half-wave id 0..7
  int row0 = blockIdx.x * 64;

  for (int rep = 0; rep < 8; ++rep) {
    int dloc = hw * 8 + rep;
    int d = row0 + dloc;
    int dc = d < N ? d : N - 1;

    int cnt = cursor[dc * CSTR];
    const int* evr = ev + dc * CAP;
    const int4* p0 = (const int4*)(evr + qloc * 8);
    int4 e0 = p0[0], e1 = p0[1];
    const int4* p1 = (const int4*)(evr + 16 + qloc * 8);
    int4 e2 = p1[0], e3 = p1[1];
    uint2 iv = {0, 0};
    if (qloc == 0) iv = ((const uint2*)(AGG1 + (size_t)dc * HID))[sub];
    if (cnt > CAP) cnt = CAP;

    float a0 = 0.f, a1 = 0.f, a2 = 0.f, a3 = 0.f;
    if (qloc == 0) {
      a0 = bflo(iv.x); a1 = bfhi(iv.x); a2 = bflo(iv.y); a3 = bfhi(iv.y);
    }
    agg_dst((const uint2*)H1, evr, e0, e1, e2, e3, cnt, qloc, sub, lhl, h,
            a0, a1, a2, a3);
    if (qloc == 0) {
      short4v s;
      s.x = f2bf(fmaxf(a0, 0.f)); s.y = f2bf(fmaxf(a1, 0.f));
      s.z = f2bf(fmaxf(a2, 0.f)); s.w = f2bf(fmaxf(a3, 0.f));
      *(short4v*)(As + dloc * AST + 4 * sub) = s;
    }
  }
  // gemm_dev's first __syncthreads (after Bs tile-0 write) orders As reads.
  gemm_dev<HID, 2>(As, Bs, nullptr, Bt2, bias2, H2, AGG2, N, row0);
}

// ---- layer-2 aggregation (2 dsts/wave) + relu -> @Wl+bl -> log_softmax -----
__global__ __launch_bounds__(256) void csr_agg_final(
    const short* __restrict__ H, const int* __restrict__ cursor,
    const int* __restrict__ ev, const unsigned short* __restrict__ AGG,
    const float* __restrict__ Wl, const float* __restrict__ bl,
    float* __restrict__ out, int N)
{
  __shared__ float sWl[HID * OUT_DIM];
  __shared__ float sbl[OUT_DIM];
  __shared__ float sh[8][HID];
  int tid = threadIdx.x;
  int wv = tid >> 6, lane = tid & 63;
  int h = lane >> 5, lhl = lane & 31, qloc = lhl >> 4, sub = lhl & 15;
  int d = blockIdx.x * 8 + wv * 2 + h;
  int dc = d < N ? d : N - 1;

  // all prologue loads issued together (independent)
  int cnt = cursor[dc * CSTR];
  const int* evr = ev + dc * CAP;
  const int4* p0 = (const int4*)(evr + qloc * 8);
  int4 e0 = p0[0], e1 = p0[1];
  const int4* p1 = (const int4*)(evr + 16 + qloc * 8);
  int4 e2 = p1[0], e3 = p1[1];
  uint2 iv = ((const uint2*)(AGG + (size_t)dc * HID))[sub];
  if (cnt > CAP) cnt = CAP;

  float a0 = 0.f, a1 = 0.f, a2 = 0.f, a3 = 0.f;
  if (qloc == 0) {
    a0 = bflo(iv.x); a1 = bfhi(iv.x); a2 = bflo(iv.y); a3 = bfhi(iv.y);
  }
  agg_dst((const uint2*)H, evr, e0, e1, e2, e3, cnt, qloc, sub, lhl, h,
          a0, a1, a2, a3);
  if (qloc == 0) {
    float4 v;
    v.x = fmaxf(a0, 0.f); v.y = fmaxf(a1, 0.f);
    v.z = fmaxf(a2, 0.f); v.w = fmaxf(a3, 0.f);
    *(float4*)(&sh[wv * 2 + h][4 * sub]) = v;   // same-wave consumer, no barrier
  }

  // cooperative Wl staging after agg (L2-hot after first blocks)
  for (int i = tid; i < HID * OUT_DIM; i += 256) sWl[i] = Wl[i];
  if (tid < OUT_DIM) sbl[tid] = bl[tid];
  __syncthreads();

  // each wave finishes its 2 dsts sequentially
  #pragma unroll
  for (int ii = 0; ii < 2; ++ii) {
    int dd = blockIdx.x * 8 + wv * 2 + ii;
    const float* row = sh[wv * 2 + ii];
    float logit = -__builtin_inff();
    if (lane < OUT_DIM) {
      float t = sbl[lane];
      #pragma unroll 8
      for (int k = 0; k < HID; ++k) t += row[k] * sWl[k * OUT_DIM + lane];
      logit = t;
    }
    float m = logit;
    #pragma unroll
    for (int o = 32; o > 0; o >>= 1) m = fmaxf(m, __shfl_xor(m, o, 64));
    float ex = (lane < OUT_DIM) ? expf(logit - m) : 0.f;
    float s = ex;
    #pragma unroll
    for (int o = 32; o > 0; o >>= 1) s += __shfl_xor(s, o, 64);
    if (dd < N && lane < OUT_DIM)
      out[(size_t)dd * OUT_DIM + lane] = logit - m - logf(s);
  }
}

// ---- launch ----------------------------------------------------------------
extern "C" void kernel_launch(void* const* d_in, const int* in_sizes, int n_in,
                              void* d_out, int out_size, void* d_ws, size_t ws_size,
                              hipStream_t stream) {
  const float* x     = (const float*)d_in[0];
  const int*   eidx  = (const int*)d_in[1];
  const int*   etype = (const int*)d_in[2];
  const float* W1    = (const float*)d_in[3];
  const float* root1 = (const float*)d_in[4];
  const float* b1    = (const float*)d_in[5];
  const float* W2    = (const float*)d_in[6];
  const float* root2 = (const float*)d_in[7];
  const float* b2    = (const float*)d_in[8];
  const float* Wl    = (const float*)d_in[9];
  const float* bl    = (const float*)d_in[10];

  int N = in_sizes[0] / IN_DIM;   // 50000
  int E = in_sizes[2];            // 800000
  const int* srcp = eidx;
  const int* dstp = eidx + E;

  char* ws = (char*)d_ws;
  size_t off = 0;
  auto alloc = [&](size_t bytes) -> char* {
    char* p = ws + off;
    off += (bytes + 255) & ~(size_t)255;
    return p;
  };
  short* Bt1    = (short*)alloc((size_t)NCOLS * IN_DIM * 2);
  short* Bt2    = (short*)alloc((size_t)NCOLS * HID * 2);
  int*   cursor = (int*)alloc((size_t)N * CSTR * 4);           // 3.2 MB padded
  int*   ev     = (int*)alloc((size_t)N * CAP * 4);            // 12.8 MB
  short* H1     = (short*)alloc((size_t)N * NREL * HID * 2);   // 51.2 MB bf16
  short* H2     = (short*)alloc((size_t)N * NREL * HID * 2);   // 51.2 MB bf16
  unsigned short* AGG1 = (unsigned short*)alloc((size_t)N * HID * 2);
  unsigned short* AGG2 = (unsigned short*)alloc((size_t)N * HID * 2);

  const int PB1 = (NCOLS * IN_DIM + 255) / 256;   // 288
  const int PB2 = (NCOLS * HID + 255) / 256;      // 144
  int nzero4 = (N * CSTR) / 4;                    // int4 count for cursor zero
  int ZB = (nzero4 + 255) / 256;                  // 782
  pack_bt<<<PB1 + PB2 + ZB, 256, 0, stream>>>(W1, root1, Bt1, W2, root2, Bt2,
                                              cursor, nzero4);

  int GB = (N + 63) / 64;          // 782 gemm blocks
  int SB = (E + 255) / 256;        // 3125 scatter blocks
  gemm1_scatter<<<GB + SB, 256, 0, stream>>>(x, Bt1, b1, H1, AGG1, N, GB,
                                             srcp, dstp, etype, cursor, ev, E);

  agg_gemm2<<<GB, 256, 0, stream>>>(H1, cursor, ev, AGG1, Bt2, b2,
                                    H2, AGG2, N);

  csr_agg_final<<<(N + 7) / 8, 256, 0, stream>>>(H2, cursor, ev, AGG2,
                                                 Wl, bl, (float*)d_out, N);
}